// Round 1
// baseline (708.519 us; speedup 1.0000x reference)
//
#include <hip/hip_runtime.h>

// HEALPix pad, p=1, H=W=256, layout [B,12,C,H,W] -> [B,12,C,258,258].
// Setup is fixed: B=2, C=64, pad=1, channels_last=False — constants hardcoded
// where the mapping depends on them (pad=1 collapses halo slabs to single
// rows/cols and tri-point corners to single averaged pixels).

#define HH 256
#define HP 258
#define FACE_ELEMS (HH * HH)     // 65536
#define OFACE_ELEMS (HP * HP)    // 66564
#define NCH 64                   // channels per face (setup-fixed)
#define HALO (2 * HP + 2 * HH)   // 1028 border pixels per output plane

// Interior: out[pi, 1+r, 1+c] = in[pi, r, c]. float4 loads (16B aligned),
// 4 scalar stores (output interior is odd-offset; dwordx4 needs 16B align).
__global__ void healpix_interior(const float* __restrict__ in,
                                 float* __restrict__ out, int total4) {
    int idx = blockIdx.x * blockDim.x + threadIdx.x;
    if (idx >= total4) return;
    int c4 = idx & 63;          // 64 float4 per 256-wide row
    int t = idx >> 6;
    int r = t & 255;
    int pi = t >> 8;
    const float4 v = *reinterpret_cast<const float4*>(
        in + (size_t)pi * FACE_ELEMS + r * HH + (c4 << 2));
    float* o = out + (size_t)pi * OFACE_ELEMS + (size_t)(r + 1) * HP + (c4 << 2) + 1;
    o[0] = v.x; o[1] = v.y; o[2] = v.z; o[3] = v.w;
}

// Halo: one thread per border pixel of each output plane.
// rot90 semantics used to resolve rotated neighbors to direct source indices:
//   rot(g, 1)[y,x] = g[x,   W-1-y]
//   rot(g, 2)[y,x] = g[H-1-y, W-1-x]
//   rot(g,-1)[y,x] = g[H-1-x, y]
__global__ void healpix_halo(const float* __restrict__ in,
                             float* __restrict__ out, int totalh) {
    int idx = blockIdx.x * blockDim.x + threadIdx.x;
    if (idx >= totalh) return;
    int h = idx % HALO;
    int pi = idx / HALO;
    int face = (pi / NCH) % 12;

    int oy, ox;
    if (h < HP)           { oy = 0;      ox = h; }
    else if (h < 2 * HP)  { oy = HP - 1; ox = h - HP; }
    else if (h < 2 * HP + HH) { ox = 0;      oy = h - 2 * HP + 1; }
    else                      { ox = HP - 1; oy = h - 2 * HP - HH + 1; }

    const int i = face & 3;
    const int type = face >> 2;   // 0 north, 1 equatorial, 2 south
    const bool top = (oy == 0), bot = (oy == HP - 1);
    const bool lft = (ox == 0), rgt = (ox == HP - 1);
    const int iy = oy - 1, ix = ox - 1;

    // neighbor-face fetch: plane index shifts by (nf - face)*NCH
    auto src = [&](int nf, int sy, int sx) -> float {
        return in[(size_t)(pi + (nf - face) * NCH) * FACE_ELEMS + sy * HH + sx];
    };

    float val;
    if (top && lft) {                              // TL corner
        if (type == 0)      val = src((i + 2) & 3, 0, 0);                 // rot2[255,255]
        else if (type == 1) val = 0.5f * (src(i, HH - 1, 0) +
                                          src((i + 3) & 3, 0, HH - 1));   // tri-point
        else                val = src(i, HH - 1, HH - 1);
    } else if (top && rgt) {                       // TR corner
        if (type == 0)      val = src((i + 1) & 3, HH - 1, HH - 1);       // rot-1[255,0]
        else if (type == 1) val = src((i + 1) & 3, HH - 1, 0);
        else                val = src(((i + 1) & 3) + 4, HH - 1, 0);
    } else if (bot && lft) {                       // BL corner
        if (type == 0)      val = src((i + 3) & 3, 0, HH - 1);
        else if (type == 1) val = src(((i + 3) & 3) + 4, 0, HH - 1);
        else                val = src(((i + 3) & 3) + 8, 0, 0);           // rot-1[0,255]
    } else if (bot && rgt) {                       // BR corner
        if (type == 0)      val = src(i + 8, 0, 0);
        else if (type == 1) val = 0.5f * (src(i + 8, 0, HH - 1) +
                                          src(((i + 1) & 3) + 4, HH - 1, 0)); // tri-point
        else                val = src(((i + 3) & 3) + 8, HH - 1, HH - 1); // rot2[0,0]
    } else if (top) {                              // top edge
        if (type == 0)      val = src((i + 1) & 3, ix, 0);                // rot1[255,ix]
        else if (type == 1) val = src(i, HH - 1, ix);
        else                val = src(i + 4, HH - 1, ix);
    } else if (bot) {                              // bottom edge
        if (type == 0)      val = src(i + 4, 0, ix);
        else if (type == 1) val = src(i + 8, 0, ix);
        else                val = src(((i + 3) & 3) + 8, ix, HH - 1);     // rot1[0,ix]
    } else if (lft) {                              // left edge
        if (type == 2)      val = src(((i + 3) & 3) + 4, iy, HH - 1);
        else                val = src((i + 3) & 3, iy, HH - 1);
    } else {                                       // right edge
        if (type == 2)      val = src(((i + 1) & 3) + 8, iy, 0);
        else                val = src(((i + 1) & 3) + 4, iy, 0);
    }

    out[(size_t)pi * OFACE_ELEMS + (size_t)oy * HP + ox] = val;
}

extern "C" void kernel_launch(void* const* d_in, const int* in_sizes, int n_in,
                              void* d_out, int out_size, void* d_ws, size_t ws_size,
                              hipStream_t stream) {
    const float* x = (const float*)d_in[0];
    float* out = (float*)d_out;

    const int P = in_sizes[0] / FACE_ELEMS;   // B*12*C = 1536 planes

    const int total4 = P * HH * (HH / 4);     // 25,165,824 float4s
    const int blk = 256;
    healpix_interior<<<(total4 + blk - 1) / blk, blk, 0, stream>>>(x, out, total4);

    const int totalh = P * HALO;              // 1,579,008 halo pixels
    healpix_halo<<<(totalh + blk - 1) / blk, blk, 0, stream>>>(x, out, totalh);
}

// Round 2
// 655.899 us; speedup vs baseline: 1.0802x; 1.0802x over previous
//
#include <hip/hip_runtime.h>

// HEALPix pad, p=1, H=W=256, layout [B,12,C,H,W] -> [B,12,C,258,258].
// Setup fixed: B=2, C=64, pad=1, channels_last=False.
//
// Strategy (R2): one fused kernel. Each block produces a CONTIGUOUS,
// 16B-aligned span of one output plane (16 full 258-wide rows, incl. halo
// columns), staged through LDS so that global stores are aligned
// global_store_dwordx4. Global loads are stride-1 coalesced scalars
// (conflict-free stride-1 LDS writes); halo cells are gathered by a few
// threads per block using the round-1-verified neighbor logic.

#define HH 256
#define HP 258
#define FACE_ELEMS (HH * HH)     // 65536
#define OFACE_ELEMS (HP * HP)    // 66564
#define NCH 64                   // channels per face (setup-fixed)

// rot90 semantics used to resolve rotated neighbors to direct source indices:
//   rot(g, 1)[y,x] = g[x,   W-1-y]
//   rot(g, 2)[y,x] = g[H-1-y, W-1-x]
//   rot(g,-1)[y,x] = g[H-1-x, y]
// This decision tree passed absmax=0 in round 1 — kept verbatim.
__device__ __forceinline__ float halo_val(const float* __restrict__ in,
                                          int pi, int face, int oy, int ox) {
    const int i = face & 3;
    const int type = face >> 2;   // 0 north, 1 equatorial, 2 south
    const bool top = (oy == 0), bot = (oy == HP - 1);
    const bool lft = (ox == 0), rgt = (ox == HP - 1);
    const int iy = oy - 1, ix = ox - 1;

    auto src = [&](int nf, int sy, int sx) -> float {
        return in[(size_t)(pi + (nf - face) * NCH) * FACE_ELEMS + sy * HH + sx];
    };

    float val;
    if (top && lft) {                              // TL corner
        if (type == 0)      val = src((i + 2) & 3, 0, 0);                 // rot2[255,255]
        else if (type == 1) val = 0.5f * (src(i, HH - 1, 0) +
                                          src((i + 3) & 3, 0, HH - 1));   // tri-point
        else                val = src(i, HH - 1, HH - 1);
    } else if (top && rgt) {                       // TR corner
        if (type == 0)      val = src((i + 1) & 3, HH - 1, HH - 1);       // rot-1[255,0]
        else if (type == 1) val = src((i + 1) & 3, HH - 1, 0);
        else                val = src(((i + 1) & 3) + 4, HH - 1, 0);
    } else if (bot && lft) {                       // BL corner
        if (type == 0)      val = src((i + 3) & 3, 0, HH - 1);
        else if (type == 1) val = src(((i + 3) & 3) + 4, 0, HH - 1);
        else                val = src(((i + 3) & 3) + 8, 0, 0);           // rot-1[0,255]
    } else if (bot && rgt) {                       // BR corner
        if (type == 0)      val = src(i + 8, 0, 0);
        else if (type == 1) val = 0.5f * (src(i + 8, 0, HH - 1) +
                                          src(((i + 1) & 3) + 4, HH - 1, 0)); // tri-point
        else                val = src(((i + 3) & 3) + 8, HH - 1, HH - 1); // rot2[0,0]
    } else if (top) {                              // top edge
        if (type == 0)      val = src((i + 1) & 3, ix, 0);                // rot1[255,ix]
        else if (type == 1) val = src(i, HH - 1, ix);
        else                val = src(i + 4, HH - 1, ix);
    } else if (bot) {                              // bottom edge
        if (type == 0)      val = src(i + 4, 0, ix);
        else if (type == 1) val = src(i + 8, 0, ix);
        else                val = src(((i + 3) & 3) + 8, ix, HH - 1);     // rot1[0,ix]
    } else if (lft) {                              // left edge
        if (type == 2)      val = src(((i + 3) & 3) + 4, iy, HH - 1);
        else                val = src((i + 3) & 3, iy, HH - 1);
    } else {                                       // right edge
        if (type == 2)      val = src(((i + 1) & 3) + 8, iy, 0);
        else                val = src(((i + 1) & 3) + 4, iy, 0);
    }
    return val;
}

// Grid: (17, P). Block b<16 covers output rows [16b, 16b+16); block 16 covers
// rows [256, 258). The covered span is contiguous in the plane and its start
// (4128*b floats, or 66048) is a multiple of 4 floats -> 16B-aligned stores.
__global__ __launch_bounds__(256)
void healpix_fused(const float* __restrict__ in, float* __restrict__ out) {
    __shared__ __align__(16) float lds[16 * HP];   // 16512 B

    const int b  = blockIdx.x;       // 0..16 row-block
    const int pi = blockIdx.y;       // plane index (B*12*C planes)
    const int face = (pi / NCH) % 12;
    const int t = threadIdx.x;

    const float* inp = in + (size_t)pi * FACE_ELEMS;
    const int oy0 = b * 16;

    if (b >= 1 && b < 16) {
        // 16 interior rows: input rows iy = oy0-1 .. oy0+14.
        // stride-1 scalar loads (coalesced 256B/instr), stride-1 LDS writes
        // (conflict-free), shifted +1 col for the halo slot.
        const int iy0 = oy0 - 1;
        #pragma unroll
        for (int k = 0; k < 16; ++k) {
            const int f = t + 256 * k;
            const int row = f >> 8, col = f & 255;
            lds[row * HP + 1 + col] = inp[(iy0 + row) * HH + col];
        }
        if (t < 16)                     // left halo col
            lds[t * HP] = halo_val(in, pi, face, oy0 + t, 0);
        else if (t < 32) {              // right halo col
            const int r = t - 16;
            lds[r * HP + HP - 1] = halo_val(in, pi, face, oy0 + r, HP - 1);
        }
    } else if (b == 0) {
        // row 0 = top halo; rows 1..15 from input rows 0..14
        for (int f = t; f < 15 * 256; f += 256) {
            const int row = f >> 8, col = f & 255;
            lds[(row + 1) * HP + 1 + col] = inp[row * HH + col];
        }
        for (int ox = t; ox < HP; ox += 256)
            lds[ox] = halo_val(in, pi, face, 0, ox);
        if (t >= 1 && t < 16)           // left halo col, rows 1..15
            lds[t * HP] = halo_val(in, pi, face, t, 0);
        else if (t >= 17 && t < 32) {   // right halo col, rows 1..15
            const int r = t - 16;
            lds[r * HP + HP - 1] = halo_val(in, pi, face, r, HP - 1);
        }
    } else {
        // b == 16: row 256 (interior, iy=255) + row 257 (bottom halo)
        if (t < 256) lds[1 + t] = inp[255 * HH + t];
        if (t == 0) lds[0]      = halo_val(in, pi, face, 256, 0);
        if (t == 1) lds[HP - 1] = halo_val(in, pi, face, 256, HP - 1);
        for (int ox = t; ox < HP; ox += 256)
            lds[HP + ox] = halo_val(in, pi, face, 257, ox);
    }

    __syncthreads();

    // Aligned contiguous store: ds_read_b128 + global_store_dwordx4.
    const int n4 = (b < 16) ? (16 * HP / 4) : (2 * HP / 4);   // 1032 or 129
    float* outbase = out + (size_t)pi * OFACE_ELEMS + (size_t)oy0 * HP;
    for (int q = t; q < n4; q += 256) {
        const float4 v = *reinterpret_cast<const float4*>(&lds[4 * q]);
        *reinterpret_cast<float4*>(&outbase[4 * q]) = v;
    }
}

extern "C" void kernel_launch(void* const* d_in, const int* in_sizes, int n_in,
                              void* d_out, int out_size, void* d_ws, size_t ws_size,
                              hipStream_t stream) {
    const float* x = (const float*)d_in[0];
    float* out = (float*)d_out;

    const int P = in_sizes[0] / FACE_ELEMS;   // B*12*C = 1536 planes
    dim3 grid(17, P);
    healpix_fused<<<grid, 256, 0, stream>>>(x, out);
}